// Round 4
// baseline (302.727 us; speedup 1.0000x reference)
//
#include <hip/hip_runtime.h>

#define RAYS 65536
#define NS   192
#define ITER 4          // ray-pairs per wave (software pipeline depth)

__device__ __forceinline__ int   f2i(float x){ return __builtin_bit_cast(int, x); }
__device__ __forceinline__ float i2f(int x)  { return __builtin_bit_cast(float, x); }

// v_mov_b32_dpp with old=0, bound_ctrl:0, bank_mask 0xF
template<int CTRL, int ROWMASK>
__device__ __forceinline__ float dpp0(float x){
    return i2f(__builtin_amdgcn_update_dpp(0, f2i(x), CTRL, ROWMASK, 0xF, true));
}
template<int OFF>
__device__ __forceinline__ float swz(float x){
    return i2f(__builtin_amdgcn_ds_swizzle(f2i(x), OFF));
}

// partner value at sub-lane distance JL (within each 32-lane half)
template<int JL>
__device__ __forceinline__ float partner(float x){
    if      constexpr (JL == 1) return dpp0<0xB1, 0xF>(x);   // quad_perm xor1
    else if constexpr (JL == 2) return dpp0<0x4E, 0xF>(x);   // quad_perm xor2
    else if constexpr (JL == 4) return swz<0x101F>(x);       // xor4
    else if constexpr (JL == 8) return swz<0x201F>(x);       // xor8
    else                        return swz<0x401F>(x);       // xor16
}

__device__ __forceinline__ void cswap(float &a, float &b, bool up){
    float mn = fminf(a, b), mx = fmaxf(a, b);
    a = up ? mn : mx;
    b = up ? mx : mn;
}

template<int J>
__device__ __forceinline__ void rphase(float v[8], bool up){
    #pragma unroll
    for (int r = 0; r < 8; ++r)
        if ((r & J) == 0) cswap(v[r], v[r ^ J], up);
}

template<int JL>
__device__ __forceinline__ void xphase(float v[8], bool takeMin){
    #pragma unroll
    for (int r = 0; r < 8; ++r){
        float p  = partner<JL>(v[r]);
        float mn = fminf(v[r], p), mx = fmaxf(v[r], p);
        v[r] = takeMin ? mn : mx;
    }
}

__device__ __forceinline__ float halfsum(float a){
    a += dpp0<0xB1, 0xF>(a);
    a += dpp0<0x4E, 0xF>(a);
    a += swz<0x101F>(a);
    a += swz<0x201F>(a);
    a += swz<0x401F>(a);
    return a;
}

__device__ __forceinline__ void load_t(const float* __restrict__ t, int ray, int sl,
                                       float v[8]){
    const float* trow = t + (size_t)ray * 193;
    if (sl < 24){
        #pragma unroll
        for (int r = 0; r < 8; ++r) v[r] = trow[8 * sl + r];
    } else if (sl == 24){
        v[0] = trow[192];
        #pragma unroll
        for (int r = 1; r < 8; ++r) v[r] = 1e30f;
    } else {
        #pragma unroll
        for (int r = 0; r < 8; ++r) v[r] = 1e30f;
    }
}

__device__ __forceinline__ void sort256(float v[8], int sl){
    bool up;
    // k=2
    cswap(v[0],v[1],true);  cswap(v[2],v[3],false);
    cswap(v[4],v[5],true);  cswap(v[6],v[7],false);
    // k=4
    cswap(v[0],v[2],true);  cswap(v[1],v[3],true);
    cswap(v[4],v[6],false); cswap(v[5],v[7],false);
    cswap(v[0],v[1],true);  cswap(v[2],v[3],true);
    cswap(v[4],v[5],false); cswap(v[6],v[7],false);
    // k=8
    up = ((sl & 1) == 0);
    rphase<4>(v, up); rphase<2>(v, up); rphase<1>(v, up);
    // k=16
    up = ((sl & 2) == 0);
    xphase<1>(v, up == ((sl & 1) == 0));
    rphase<4>(v, up); rphase<2>(v, up); rphase<1>(v, up);
    // k=32
    up = ((sl & 4) == 0);
    xphase<2>(v, up == ((sl & 2) == 0));
    xphase<1>(v, up == ((sl & 1) == 0));
    rphase<4>(v, up); rphase<2>(v, up); rphase<1>(v, up);
    // k=64
    up = ((sl & 8) == 0);
    xphase<4>(v, up == ((sl & 4) == 0));
    xphase<2>(v, up == ((sl & 2) == 0));
    xphase<1>(v, up == ((sl & 1) == 0));
    rphase<4>(v, up); rphase<2>(v, up); rphase<1>(v, up);
    // k=128
    up = ((sl & 16) == 0);
    xphase<8>(v, up == ((sl & 8) == 0));
    xphase<4>(v, up == ((sl & 4) == 0));
    xphase<2>(v, up == ((sl & 2) == 0));
    xphase<1>(v, up == ((sl & 1) == 0));
    rphase<4>(v, up); rphase<2>(v, up); rphase<1>(v, up);
    // k=256
    xphase<16>(v, ((sl & 16) == 0));
    xphase<8> (v, ((sl & 8)  == 0));
    xphase<4> (v, ((sl & 4)  == 0));
    xphase<2> (v, ((sl & 2)  == 0));
    xphase<1> (v, ((sl & 1)  == 0));
    rphase<4>(v, true); rphase<2>(v, true); rphase<1>(v, true);
}

__global__ __launch_bounds__(256) void nerf_integrate(
    const float* __restrict__ t,
    const float* __restrict__ sigma,
    const float* __restrict__ c,
    float* __restrict__ out)
{
    const int tid  = threadIdx.x;
    const int lane = tid & 63;
    const int sl   = tid & 31;
    // wave handles ITER ray-pairs; block covers 32 consecutive rays
    const int ray0 = blockIdx.x * (8 * ITER) + ((tid >> 6) << 1) + ((tid >> 5) & 1);

    float tn_buf[8];
    load_t(t, ray0, sl, tn_buf);                 // prefetch iter 0

    #pragma unroll
    for (int it = 0; it < ITER; ++it){
        const int ray = ray0 + it * 8;
        float v[8];
        #pragma unroll
        for (int r = 0; r < 8; ++r) v[r] = tn_buf[r];

        // ---- prefetch next iteration's t + this iteration's sigma & c ----
        if (it + 1 < ITER) load_t(t, ray + 8, sl, tn_buf);
        const bool act = (sl < 24);
        float sg[8];
        float cf[24];
        if (act){
            const float* srow = sigma + (size_t)ray * NS + 8 * sl;
            float4 s0 = *reinterpret_cast<const float4*>(srow);
            float4 s1 = *reinterpret_cast<const float4*>(srow + 4);
            sg[0]=s0.x; sg[1]=s0.y; sg[2]=s0.z; sg[3]=s0.w;
            sg[4]=s1.x; sg[5]=s1.y; sg[6]=s1.z; sg[7]=s1.w;
            const float* crow = c + (size_t)ray * (NS * 3) + 24 * sl;
            #pragma unroll
            for (int m = 0; m < 6; ++m){
                float4 cc = *reinterpret_cast<const float4*>(crow + 4 * m);
                cf[4*m+0]=cc.x; cf[4*m+1]=cc.y; cf[4*m+2]=cc.z; cf[4*m+3]=cc.w;
            }
        } else {
            #pragma unroll
            for (int r = 0; r < 8; ++r) sg[r] = 0.0f;
            #pragma unroll
            for (int m = 0; m < 24; ++m) cf[m] = 0.0f;
        }

        // ---- sort (hides the prefetch latency) ----
        sort256(v, sl);

        // ---- neighbor for r=7 ----
        float nxt = __shfl(v[0], lane + 1, 64);

        float sdt[8];
        #pragma unroll
        for (int r = 0; r < 8; ++r){
            float tn = (r < 7) ? v[r + 1] : nxt;
            sdt[r] = act ? sg[r] * (tn - v[r]) : 0.0f;
        }

        // ---- prefix sum: in-lane over 8, then per-half DPP scan ----
        float pre[8];
        float run = 0.0f;
        #pragma unroll
        for (int r = 0; r < 8; ++r){ run += sdt[r]; pre[r] = run; }
        float x = run;
        x += dpp0<0x111, 0xF>(x);   // row_shr:1
        x += dpp0<0x112, 0xF>(x);   // row_shr:2
        x += dpp0<0x114, 0xF>(x);   // row_shr:4
        x += dpp0<0x118, 0xF>(x);   // row_shr:8
        x += dpp0<0x142, 0xA>(x);   // row_bcast:15 -> rows 1,3
        float laneExcl = x - run;

        // ---- wi = exp(-excl) - exp(-incl) ----
        float wi[8];
        #pragma unroll
        for (int r = 0; r < 8; ++r){
            float incl = laneExcl + pre[r];
            float excl = incl - sdt[r];
            wi[r] = __expf(-excl) - __expf(-incl);
        }
        if (act){
            float* wrow = out + (size_t)RAYS * 3 + (size_t)ray * NS + 8 * sl;
            *reinterpret_cast<float4*>(wrow)     = make_float4(wi[0], wi[1], wi[2], wi[3]);
            *reinterpret_cast<float4*>(wrow + 4) = make_float4(wi[4], wi[5], wi[6], wi[7]);
        }

        // ---- rgb accumulate + per-half reduce ----
        float a0 = 0.f, a1 = 0.f, a2 = 0.f;
        #pragma unroll
        for (int r = 0; r < 8; ++r){
            a0 += wi[r] * cf[3*r + 0];
            a1 += wi[r] * cf[3*r + 1];
            a2 += wi[r] * cf[3*r + 2];
        }
        if (!act){ a0 = 0.f; a1 = 0.f; a2 = 0.f; }
        a0 = halfsum(a0);
        a1 = halfsum(a1);
        a2 = halfsum(a2);
        if (sl < 3){
            float val = (sl == 0) ? a0 : ((sl == 1) ? a1 : a2);
            out[(size_t)ray * 3 + sl] = val;
        }
    }
}

extern "C" void kernel_launch(void* const* d_in, const int* in_sizes, int n_in,
                              void* d_out, int out_size, void* d_ws, size_t ws_size,
                              hipStream_t stream) {
    const float* t     = (const float*)d_in[0];
    const float* sigma = (const float*)d_in[1];
    const float* c     = (const float*)d_in[2];
    float* out = (float*)d_out;
    nerf_integrate<<<RAYS / (8 * ITER), 256, 0, stream>>>(t, sigma, c, out);
}